// Round 7
// baseline (131.479 us; speedup 1.0000x reference)
//
#include <hip/hip_runtime.h>
#include <hip/hip_cooperative_groups.h>

namespace cg = cooperative_groups;

#define DD 128
#define LL 512
#define BB 2
#define NK (BB * LL)   // 1024 global rows

// ---- Single fused cooperative kernel. Grid = 256 blocks (1/CU), 512 threads.
// Proj phase: block bx computes Es rows [bx*4, bx*4+4) (its OWN queries) and
//             Eh rows [bx*4, bx*4+4), i.e. exp(2*row@W) / exp(2*row@U).
// grid.sync(), then the R5 attention phase (scalar PAIR algebra) verbatim.
__global__ __launch_bounds__(512, 1)
void fused_kernel(const float* __restrict__ s, const float* __restrict__ h,
                  const float* __restrict__ W, const float* __restrict__ U,
                  const float* __restrict__ v,
                  float* __restrict__ Es, float* __restrict__ EhT4,
                  float* __restrict__ out) {
    __shared__ float xr[8 * DD];          // 4 KB: 4 s-rows + 4 h-rows, x2 pre-scale
    __shared__ float4 p4[LL];             // 8 KB: p per (key, 4 queries)
    __shared__ float4 wsum4[8];           // per-wave exp-sums
    __shared__ float red[8][4][DD];       // 16 KB: PV partials

    int bx = blockIdx.x;                  // 0..255
    int row0 = bx * 4;                    // this block's 4 global rows
    int b = bx >> 7;
    int t = threadIdx.x;
    int lane = t & 63;
    int w = __builtin_amdgcn_readfirstlane(t >> 6);   // uniform wave id

    // ======== proj phase ========
    {
        int e2 = t * 2;                   // 1024 floats = 8 rows x 128
        int row8 = e2 >> 7;               // 0..3 -> s, 4..7 -> h
        int col = e2 & 127;
        const float* src = (row8 < 4) ? s : h;
        int grow = row0 + (row8 & 3);
        float2 xv = *(const float2*)&src[(size_t)grow * DD + col];
        xr[row8 * DD + col]     = 2.f * xv.x;
        xr[row8 * DD + col + 1] = 2.f * xv.y;
    }
    __syncthreads();
    if (t < 256) {                        // waves 0-3: GEMM; 4-7 idle (short phase)
        int half = t >> 7;                // 0 = Es (W,s), 1 = Eh (U,h); wave-uniform
        int r = (t >> 5) & 3;
        int cg4 = (t & 31) * 4;
        const float* M = half ? U : W;
        const float* xrow = &xr[(half * 4 + r) * DD];
        float4 acc = make_float4(0.f, 0.f, 0.f, 0.f);
#pragma unroll 8
        for (int d = 0; d < DD; ++d) {
            float4 m = *(const float4*)&M[d * DD + cg4];   // dwordx4, L2-resident
            float xb = xrow[d];           // 2-way LDS broadcast (free)
            acc.x = fmaf(xb, m.x, acc.x);
            acc.y = fmaf(xb, m.y, acc.y);
            acc.z = fmaf(xb, m.z, acc.z);
            acc.w = fmaf(xb, m.w, acc.w);
        }
        float4 e;
        e.x = __expf(acc.x); e.y = __expf(acc.y);
        e.z = __expf(acc.z); e.w = __expf(acc.w);
        int row = row0 + r;
        if (half == 0) {
            *(float4*)&Es[(size_t)row * DD + cg4] = e;                // row-major
        } else {
            *(float4*)&EhT4[((size_t)(cg4 >> 2) * NK + row) * 4] = e; // tiled f4
        }
    }
    cg::this_grid().sync();

    // ======== attn phase (R5 verbatim) ========
    // Per d-PAIR per query, one rcp:
    //   vx/(1+Ex)+vy/(1+Ey) = [vx*Ey+vy*Ex + (vx+vy)] / [(1+Ex)(1+Ey)],
    // E = Es(q,d)*Eh(j,d); exps precomputed, no exp in hot loop.
    int j = w * 64 + lane;                // key within batch
    int kk = b * LL + j;                  // global key row
    const float4* hp = (const float4*)EhT4 + kk;      // stride NK float4 per d-grp
    const float* es0 = Es + (size_t)row0 * DD;        // uniform -> scalar loads
    float ac0 = 0.f, ac1 = 0.f, ac2 = 0.f, ac3 = 0.f; // num*r parts
    float cc0 = 0.f, cc1 = 0.f, cc2 = 0.f, cc3 = 0.f; // vsum*r parts
#pragma unroll 4
    for (int dg = 0; dg < 32; ++dg) {
        float4 E  = hp[(size_t)dg * NK];              // Eh, coalesced 1 KB/wave
        float4 q0 = *(const float4*)(es0 + 0 * DD + dg * 4);  // wave-uniform
        float4 q1 = *(const float4*)(es0 + 1 * DD + dg * 4);
        float4 q2 = *(const float4*)(es0 + 2 * DD + dg * 4);
        float4 q3 = *(const float4*)(es0 + 3 * DD + dg * 4);
        float4 vv = *(const float4*)(v + dg * 4);
        float vsxy = vv.x + vv.y;
        float vszw = vv.z + vv.w;
#define PAIR(eqx, eqy, Ehx, Ehy, vx, vy, vs, ACC, CCC)                    \
        {                                                                 \
            float Ex = eqx * Ehx;                                         \
            float Ey = eqy * Ehy;                                         \
            float uy = Ey + 1.f;                                          \
            float den = fmaf(Ex, uy, uy);                                 \
            float r = __builtin_amdgcn_rcpf(den);                         \
            float num = fmaf(vx, Ey, vy * Ex);                            \
            ACC = fmaf(num, r, ACC);                                      \
            CCC = fmaf(vs, r, CCC);                                       \
        }
        PAIR(q0.x, q0.y, E.x, E.y, vv.x, vv.y, vsxy, ac0, cc0)
        PAIR(q0.z, q0.w, E.z, E.w, vv.z, vv.w, vszw, ac0, cc0)
        PAIR(q1.x, q1.y, E.x, E.y, vv.x, vv.y, vsxy, ac1, cc1)
        PAIR(q1.z, q1.w, E.z, E.w, vv.z, vv.w, vszw, ac1, cc1)
        PAIR(q2.x, q2.y, E.x, E.y, vv.x, vv.y, vsxy, ac2, cc2)
        PAIR(q2.z, q2.w, E.z, E.w, vv.z, vv.w, vszw, ac2, cc2)
        PAIR(q3.x, q3.y, E.x, E.y, vv.x, vv.y, vsxy, ac3, cc3)
        PAIR(q3.z, q3.w, E.z, E.w, vv.z, vv.w, vszw, ac3, cc3)
#undef PAIR
    }
    // score = sum_d v_d*tanh = (const) - 2*acc; const is softmax-invariant.
    float p0 = __expf(-2.f * (ac0 + cc0));
    float p1 = __expf(-2.f * (ac1 + cc1));
    float p2 = __expf(-2.f * (ac2 + cc2));
    float p3 = __expf(-2.f * (ac3 + cc3));
    p4[j] = make_float4(p0, p1, p2, p3);
    float m0 = p0, m1 = p1, m2 = p2, m3 = p3;
#pragma unroll
    for (int o = 1; o < 64; o <<= 1) {
        m0 += __shfl_xor(m0, o);
        m1 += __shfl_xor(m1, o);
        m2 += __shfl_xor(m2, o);
        m3 += __shfl_xor(m3, o);
    }
    if (lane == 0) wsum4[w] = make_float4(m0, m1, m2, m3);
    __syncthreads();

    // ---- PV: wave w keys [w*64,+64), 2 keys/iter (halves), lane d4 ----
    int half = lane >> 5;
    int d4 = (lane & 31) * 4;
    const float* hb = h + (size_t)b * LL * DD;
    float4 A0 = make_float4(0.f, 0.f, 0.f, 0.f), A1 = A0, A2 = A0, A3 = A0;
#pragma unroll 4
    for (int jj = 0; jj < 32; ++jj) {
        int jl = w * 64 + jj * 2 + half;
        float4 hv = *(const float4*)&hb[jl * DD + d4];   // contiguous 1 KB/wave
        float4 pp = p4[jl];                               // b128 broadcast
        A0.x = fmaf(pp.x, hv.x, A0.x); A0.y = fmaf(pp.x, hv.y, A0.y);
        A0.z = fmaf(pp.x, hv.z, A0.z); A0.w = fmaf(pp.x, hv.w, A0.w);
        A1.x = fmaf(pp.y, hv.x, A1.x); A1.y = fmaf(pp.y, hv.y, A1.y);
        A1.z = fmaf(pp.y, hv.z, A1.z); A1.w = fmaf(pp.y, hv.w, A1.w);
        A2.x = fmaf(pp.z, hv.x, A2.x); A2.y = fmaf(pp.z, hv.y, A2.y);
        A2.z = fmaf(pp.z, hv.z, A2.z); A2.w = fmaf(pp.z, hv.w, A2.w);
        A3.x = fmaf(pp.w, hv.x, A3.x); A3.y = fmaf(pp.w, hv.y, A3.y);
        A3.z = fmaf(pp.w, hv.z, A3.z); A3.w = fmaf(pp.w, hv.w, A3.w);
    }
#define FOLD(A) A.x += __shfl_xor(A.x, 32); A.y += __shfl_xor(A.y, 32); \
                A.z += __shfl_xor(A.z, 32); A.w += __shfl_xor(A.w, 32);
    FOLD(A0) FOLD(A1) FOLD(A2) FOLD(A3)
#undef FOLD
    if (half == 0) {
        *(float4*)&red[w][0][d4] = A0;
        *(float4*)&red[w][1][d4] = A1;
        *(float4*)&red[w][2][d4] = A2;
        *(float4*)&red[w][3][d4] = A3;
    }
    __syncthreads();

    // ---- epilogue: sum 8 wave-partials, normalize, store ----
    {
        int q = t >> 7, d = t & 127;
        float o = 0.f;
#pragma unroll
        for (int k = 0; k < 8; ++k) o += red[k][q][d];
        const float* wf = (const float*)wsum4;
        float qs = 0.f;
#pragma unroll
        for (int k = 0; k < 8; ++k) qs += wf[k * 4 + q];
        out[(size_t)(row0 + q) * DD + d] = o * __builtin_amdgcn_rcpf(qs);
    }
}

extern "C" void kernel_launch(void* const* d_in, const int* in_sizes, int n_in,
                              void* d_out, int out_size, void* d_ws, size_t ws_size,
                              hipStream_t stream) {
    const float* s = (const float*)d_in[0];
    const float* h = (const float*)d_in[1];
    const float* W = (const float*)d_in[2];
    const float* U = (const float*)d_in[3];
    const float* v = (const float*)d_in[4];
    float* out = (float*)d_out;
    float* ws  = (float*)d_ws;

    float* Es   = ws;                     // 1024*128 floats: exp(2*s@W)
    float* EhT4 = ws + 131072;            // 1024*128 floats: exp(2*h@U), tiled

    void* args[] = {(void*)&s, (void*)&h, (void*)&W, (void*)&U, (void*)&v,
                    (void*)&Es, (void*)&EhT4, (void*)&out};
    hipLaunchCooperativeKernel((void*)fused_kernel, dim3(NK / 4), dim3(512),
                               args, 0, stream);
}

// Round 8
// 83.922 us; speedup vs baseline: 1.5667x; 1.5667x over previous
//
#include <hip/hip_runtime.h>

#define DD 128
#define LL 512
#define BB 2
#define NK (BB * LL)   // 1024 global rows

// ---- Kernel 1: Es = exp(2*s@W) row-major [NK][DD];
//                EhT4 = exp(2*h@U) tiled [d>>2][key][d&3] (float4-contiguous).
// 256 blocks x 256 thr; 8 rows/block; float4 loads/stores throughout.
__global__ __launch_bounds__(256)
void proj_kernel(const float* __restrict__ s, const float* __restrict__ h,
                 const float* __restrict__ W, const float* __restrict__ U,
                 float* __restrict__ Es, float* __restrict__ EhT4) {
    __shared__ float xr[8 * DD];          // 4 KB: 8 rows, pre-scaled by 2
    int bx = blockIdx.x;                  // 0..255
    bool second = bx >= 128;
    const float* X = second ? h : s;
    const float* M = second ? U : W;
    int row0 = (bx & 127) * 8;
    int t = threadIdx.x;
    {
        float4 xv = *(const float4*)&X[row0 * DD + t * 4];   // coalesced 16B
        xv.x *= 2.f; xv.y *= 2.f; xv.z *= 2.f; xv.w *= 2.f;
        *(float4*)&xr[t * 4] = xv;
    }
    __syncthreads();
    int r = t >> 5, cg = (t & 31) * 4;    // row 0..7, col group
    const float* xrow = &xr[r * DD];
    float4 acc = make_float4(0.f, 0.f, 0.f, 0.f);
#pragma unroll 8
    for (int d = 0; d < DD; ++d) {
        float4 m = *(const float4*)&M[d * DD + cg];   // dwordx4, L2-resident
        float xb = xrow[d];                           // 2-way LDS broadcast (free)
        acc.x = fmaf(xb, m.x, acc.x);
        acc.y = fmaf(xb, m.y, acc.y);
        acc.z = fmaf(xb, m.z, acc.z);
        acc.w = fmaf(xb, m.w, acc.w);
    }
    float4 e;
    e.x = __expf(acc.x); e.y = __expf(acc.y);
    e.z = __expf(acc.z); e.w = __expf(acc.w);
    int row = row0 + r;
    if (!second) {
        *(float4*)&Es[row * DD + cg] = e;
    } else {
        *(float4*)&EhT4[((size_t)(cg >> 2) * NK + row) * 4] = e;  // contiguous f4
    }
}

// ---- Kernel 2: fused attention (R5-proven scalar PAIR). Block = 4 queries x
// all 512 keys, 512 thr. Wave w owns keys [w*64,+64), 1 key/lane.
// Per d-PAIR per query: one rcp:
//   v_x/(1+Ex) + v_y/(1+Ey) = [v_x*Ey + v_y*Ex + (v_x+v_y)] / [(1+Ex)(1+Ey)]
// with Ex = Es(q,d)*Eh(j,d) (exps precomputed; no exp in hot loop).
__global__ __launch_bounds__(512, 2)
void attn_kernel(const float* __restrict__ Es, const float* __restrict__ EhT4,
                 const float* __restrict__ h, const float* __restrict__ v,
                 float* __restrict__ out) {
    __shared__ float4 p4[LL];             // p per (key, 4 queries)   8 KB
    __shared__ float4 wsum4[8];           // per-wave exp-sums (4 q)
    __shared__ float red[8][4][DD];       // PV partials             16 KB

    int bx = blockIdx.x;                  // 0..255
    int row0 = bx * 4;                    // global query rows row0..row0+3
    int b = bx >> 7;
    int t = threadIdx.x;
    int lane = t & 63;
    int w = __builtin_amdgcn_readfirstlane(t >> 6);   // uniform wave id

    // ---- phase 1: scores for 4 queries, 1 key per lane ----
    int j = w * 64 + lane;                // key within batch
    int kk = b * LL + j;                  // global key row
    const float4* hp = (const float4*)EhT4 + kk;      // stride NK float4 per d-grp
    const float* es0 = Es + (size_t)row0 * DD;        // uniform -> scalar loads
    float ac0 = 0.f, ac1 = 0.f, ac2 = 0.f, ac3 = 0.f; // num*r parts
    float cc0 = 0.f, cc1 = 0.f, cc2 = 0.f, cc3 = 0.f; // vsum*r parts
#pragma unroll 4
    for (int dg = 0; dg < 32; ++dg) {
        float4 E  = hp[(size_t)dg * NK];              // Eh, coalesced 1 KB/wave
        float4 q0 = *(const float4*)(es0 + 0 * DD + dg * 4);  // wave-uniform
        float4 q1 = *(const float4*)(es0 + 1 * DD + dg * 4);
        float4 q2 = *(const float4*)(es0 + 2 * DD + dg * 4);
        float4 q3 = *(const float4*)(es0 + 3 * DD + dg * 4);
        float4 vv = *(const float4*)(v + dg * 4);
        float vsxy = vv.x + vv.y;
        float vszw = vv.z + vv.w;
#define PAIR(eqx, eqy, Ehx, Ehy, vx, vy, vs, ACC, CCC)                    \
        {                                                                 \
            float Ex = eqx * Ehx;                                         \
            float Ey = eqy * Ehy;                                         \
            float uy = Ey + 1.f;                                          \
            float den = fmaf(Ex, uy, uy);                                 \
            float r = __builtin_amdgcn_rcpf(den);                         \
            float num = fmaf(vx, Ey, vy * Ex);                            \
            ACC = fmaf(num, r, ACC);                                      \
            CCC = fmaf(vs, r, CCC);                                       \
        }
        PAIR(q0.x, q0.y, E.x, E.y, vv.x, vv.y, vsxy, ac0, cc0)
        PAIR(q0.z, q0.w, E.z, E.w, vv.z, vv.w, vszw, ac0, cc0)
        PAIR(q1.x, q1.y, E.x, E.y, vv.x, vv.y, vsxy, ac1, cc1)
        PAIR(q1.z, q1.w, E.z, E.w, vv.z, vv.w, vszw, ac1, cc1)
        PAIR(q2.x, q2.y, E.x, E.y, vv.x, vv.y, vsxy, ac2, cc2)
        PAIR(q2.z, q2.w, E.z, E.w, vv.z, vv.w, vszw, ac2, cc2)
        PAIR(q3.x, q3.y, E.x, E.y, vv.x, vv.y, vsxy, ac3, cc3)
        PAIR(q3.z, q3.w, E.z, E.w, vv.z, vv.w, vszw, ac3, cc3)
#undef PAIR
    }
    // score = sum_d v_d*tanh = (const) - 2*acc; const is softmax-invariant.
    float p0 = __expf(-2.f * (ac0 + cc0));
    float p1 = __expf(-2.f * (ac1 + cc1));
    float p2 = __expf(-2.f * (ac2 + cc2));
    float p3 = __expf(-2.f * (ac3 + cc3));
    p4[j] = make_float4(p0, p1, p2, p3);
    float m0 = p0, m1 = p1, m2 = p2, m3 = p3;
#pragma unroll
    for (int o = 1; o < 64; o <<= 1) {
        m0 += __shfl_xor(m0, o);
        m1 += __shfl_xor(m1, o);
        m2 += __shfl_xor(m2, o);
        m3 += __shfl_xor(m3, o);
    }
    if (lane == 0) wsum4[w] = make_float4(m0, m1, m2, m3);
    __syncthreads();

    // ---- phase 3: PV. Wave w keys [w*64,+64), 2 keys/iter (halves), lane d4.
    int half = lane >> 5;
    int d4 = (lane & 31) * 4;
    const float* hb = h + (size_t)b * LL * DD;
    float4 A0 = make_float4(0.f, 0.f, 0.f, 0.f), A1 = A0, A2 = A0, A3 = A0;
#pragma unroll 4
    for (int jj = 0; jj < 32; ++jj) {
        int jl = w * 64 + jj * 2 + half;
        float4 hv = *(const float4*)&hb[jl * DD + d4];   // contiguous 1 KB/wave
        float4 pp = p4[jl];                               // b128 broadcast
        A0.x = fmaf(pp.x, hv.x, A0.x); A0.y = fmaf(pp.x, hv.y, A0.y);
        A0.z = fmaf(pp.x, hv.z, A0.z); A0.w = fmaf(pp.x, hv.w, A0.w);
        A1.x = fmaf(pp.y, hv.x, A1.x); A1.y = fmaf(pp.y, hv.y, A1.y);
        A1.z = fmaf(pp.y, hv.z, A1.z); A1.w = fmaf(pp.y, hv.w, A1.w);
        A2.x = fmaf(pp.z, hv.x, A2.x); A2.y = fmaf(pp.z, hv.y, A2.y);
        A2.z = fmaf(pp.z, hv.z, A2.z); A2.w = fmaf(pp.z, hv.w, A2.w);
        A3.x = fmaf(pp.w, hv.x, A3.x); A3.y = fmaf(pp.w, hv.y, A3.y);
        A3.z = fmaf(pp.w, hv.z, A3.z); A3.w = fmaf(pp.w, hv.w, A3.w);
    }
#define FOLD(A) A.x += __shfl_xor(A.x, 32); A.y += __shfl_xor(A.y, 32); \
                A.z += __shfl_xor(A.z, 32); A.w += __shfl_xor(A.w, 32);
    FOLD(A0) FOLD(A1) FOLD(A2) FOLD(A3)
#undef FOLD
    if (half == 0) {
        *(float4*)&red[w][0][d4] = A0;
        *(float4*)&red[w][1][d4] = A1;
        *(float4*)&red[w][2][d4] = A2;
        *(float4*)&red[w][3][d4] = A3;
    }
    __syncthreads();

    // ---- epilogue: sum 8 wave-partials, normalize, store ----
    {
        int q = t >> 7, d = t & 127;
        float o = 0.f;
#pragma unroll
        for (int k = 0; k < 8; ++k) o += red[k][q][d];
        const float* wf = (const float*)wsum4;
        float qs = 0.f;
#pragma unroll
        for (int k = 0; k < 8; ++k) qs += wf[k * 4 + q];
        out[(size_t)(row0 + q) * DD + d] = o * __builtin_amdgcn_rcpf(qs);
    }
}

extern "C" void kernel_launch(void* const* d_in, const int* in_sizes, int n_in,
                              void* d_out, int out_size, void* d_ws, size_t ws_size,
                              hipStream_t stream) {
    const float* s = (const float*)d_in[0];
    const float* h = (const float*)d_in[1];
    const float* W = (const float*)d_in[2];
    const float* U = (const float*)d_in[3];
    const float* v = (const float*)d_in[4];
    float* out = (float*)d_out;
    float* ws  = (float*)d_ws;

    float* Es   = ws;                     // 1024*128 floats: exp(2*s@W)
    float* EhT4 = ws + 131072;            // 1024*128 floats: exp(2*h@U), tiled

    hipLaunchKernelGGL(proj_kernel, dim3(256), dim3(256), 0, stream,
                       s, h, W, U, Es, EhT4);
    hipLaunchKernelGGL(attn_kernel, dim3(NK / 4), dim3(512), 0, stream,
                       Es, EhT4, h, v, out);
}

// Round 9
// 82.692 us; speedup vs baseline: 1.5900x; 1.0149x over previous
//
#include <hip/hip_runtime.h>

#define DD 128
#define LL 512
#define BB 2
#define NK (BB * LL)   // 1024 global rows

// ---- Kernel 1: Es = exp(2*s@W) row-major [NK][DD];
//                EhT4 = exp(2*h@U) tiled [d>>2][key][d&3].
// The 2x is folded into the LDS load of the x-row. 512 blocks x 256 thr.
// NOTE: this 512-block scalar-M-load version measured 3.4 us FASTER than the
// 256-block float4-load variant (R5 vs R8) — 2 blocks/CU hides M-load latency.
__global__ __launch_bounds__(256)
void proj_kernel(const float* __restrict__ s, const float* __restrict__ h,
                 const float* __restrict__ W, const float* __restrict__ U,
                 float* __restrict__ Es, float* __restrict__ EhT4) {
    __shared__ float xr[4 * DD];
    int bx = blockIdx.x;
    bool second = bx >= 256;
    const float* X = second ? h : s;
    const float* M = second ? U : W;
    int row0 = (bx & 255) * 4;            // global row (b*L + i)
    int t = threadIdx.x;
    xr[t]       = 2.0f * X[row0 * DD + t];
    xr[t + 256] = 2.0f * X[row0 * DD + 256 + t];
    __syncthreads();
    int c = t & 127, g = t >> 7;
    const float* x0 = &xr[(2 * g) * DD];
    const float* x1 = &xr[(2 * g + 1) * DD];
    float a0 = 0.f, a1 = 0.f;
#pragma unroll 8
    for (int d = 0; d < DD; ++d) {
        float m = M[d * DD + c];          // coalesced, L2-resident
        a0 = fmaf(x0[d], m, a0);
        a1 = fmaf(x1[d], m, a1);
    }
    float e0 = __expf(a0);                // exp(2*proj), |arg| <~ 12: safe
    float e1 = __expf(a1);
    if (!second) {
        Es[(row0 + 2 * g) * DD + c]     = e0;
        Es[(row0 + 2 * g + 1) * DD + c] = e1;
    } else {
        int base = (c >> 2) * (NK * 4) + (c & 3);   // tiled transpose
        EhT4[base + (row0 + 2 * g) * 4]     = e0;
        EhT4[base + (row0 + 2 * g + 1) * 4] = e1;
    }
}

// ---- Kernel 2: fused attention. Block = 4 queries x all 512 keys, 512 thr.
// Wave w owns keys [w*64,+64), 1 key/lane. Per d-PAIR per query: one rcp.
//   v_x/(1+Ex) + v_y/(1+Ey) = [v_x*Ey + v_y*Ex + (v_x+v_y)] / [(1+Ex)(1+Ey)]
// with Ex = Es(q,d)*Eh(j,d) (exp precomputed; no exp in hot loop).
__global__ __launch_bounds__(512, 2)
void attn_kernel(const float* __restrict__ Es, const float* __restrict__ EhT4,
                 const float* __restrict__ h, const float* __restrict__ v,
                 float* __restrict__ out) {
    __shared__ float4 p4[LL];             // p per (key, 4 queries)   8 KB
    __shared__ float4 wsum4[8];           // per-wave exp-sums (4 q)
    __shared__ float red[8][4][DD];       // PV partials             16 KB

    int bx = blockIdx.x;                  // 0..255
    int row0 = bx * 4;                    // global query rows row0..row0+3
    int b = bx >> 7;
    int t = threadIdx.x;
    int lane = t & 63;
    int w = __builtin_amdgcn_readfirstlane(t >> 6);   // uniform wave id

    // ---- phase 1: scores for 4 queries, 1 key per lane ----
    int j = w * 64 + lane;                // key within batch
    int kk = b * LL + j;                  // global key row
    const float4* hp = (const float4*)EhT4 + kk;      // stride NK float4 per d-group
    const float* es0 = Es + (size_t)row0 * DD;        // uniform -> scalar loads
    float ac0 = 0.f, ac1 = 0.f, ac2 = 0.f, ac3 = 0.f; // num*r parts
    float cc0 = 0.f, cc1 = 0.f, cc2 = 0.f, cc3 = 0.f; // vsum*r parts
#pragma unroll 4
    for (int dg = 0; dg < 32; ++dg) {
        float4 E  = hp[(size_t)dg * NK];              // Eh, coalesced 1 KB/wave
        float4 q0 = *(const float4*)(es0 + 0 * DD + dg * 4);  // wave-uniform
        float4 q1 = *(const float4*)(es0 + 1 * DD + dg * 4);
        float4 q2 = *(const float4*)(es0 + 2 * DD + dg * 4);
        float4 q3 = *(const float4*)(es0 + 3 * DD + dg * 4);
        float4 vv = *(const float4*)(v + dg * 4);
        float vsxy = vv.x + vv.y;                     // scalar adds
        float vszw = vv.z + vv.w;
#define PAIR(eqx, eqy, Ehx, Ehy, vx, vy, vs, ACC, CCC)                    \
        {                                                                 \
            float Ex = eqx * Ehx;                                         \
            float Ey = eqy * Ehy;                                         \
            float uy = Ey + 1.f;                                          \
            float den = fmaf(Ex, uy, uy);                                 \
            float r = __builtin_amdgcn_rcpf(den);                         \
            float num = fmaf(vx, Ey, vy * Ex);                            \
            ACC = fmaf(num, r, ACC);                                      \
            CCC = fmaf(vs, r, CCC);                                       \
        }
        PAIR(q0.x, q0.y, E.x, E.y, vv.x, vv.y, vsxy, ac0, cc0)
        PAIR(q0.z, q0.w, E.z, E.w, vv.z, vv.w, vszw, ac0, cc0)
        PAIR(q1.x, q1.y, E.x, E.y, vv.x, vv.y, vsxy, ac1, cc1)
        PAIR(q1.z, q1.w, E.z, E.w, vv.z, vv.w, vszw, ac1, cc1)
        PAIR(q2.x, q2.y, E.x, E.y, vv.x, vv.y, vsxy, ac2, cc2)
        PAIR(q2.z, q2.w, E.z, E.w, vv.z, vv.w, vszw, ac2, cc2)
        PAIR(q3.x, q3.y, E.x, E.y, vv.x, vv.y, vsxy, ac3, cc3)
        PAIR(q3.z, q3.w, E.z, E.w, vv.z, vv.w, vszw, ac3, cc3)
#undef PAIR
    }
    // score = sum_d v_d*tanh = (const) - 2*acc; const is softmax-invariant.
    float p0 = __expf(-2.f * (ac0 + cc0));
    float p1 = __expf(-2.f * (ac1 + cc1));
    float p2 = __expf(-2.f * (ac2 + cc2));
    float p3 = __expf(-2.f * (ac3 + cc3));
    p4[j] = make_float4(p0, p1, p2, p3);
    float m0 = p0, m1 = p1, m2 = p2, m3 = p3;
#pragma unroll
    for (int o = 1; o < 64; o <<= 1) {
        m0 += __shfl_xor(m0, o);
        m1 += __shfl_xor(m1, o);
        m2 += __shfl_xor(m2, o);
        m3 += __shfl_xor(m3, o);
    }
    if (lane == 0) wsum4[w] = make_float4(m0, m1, m2, m3);
    __syncthreads();

    // ---- phase 3: PV. Wave w keys [w*64,+64), 2 keys/iter (halves), lane d4.
    int half = lane >> 5;
    int d4 = (lane & 31) * 4;
    const float* hb = h + (size_t)b * LL * DD;
    float4 A0 = make_float4(0.f, 0.f, 0.f, 0.f), A1 = A0, A2 = A0, A3 = A0;
#pragma unroll 4
    for (int jj = 0; jj < 32; ++jj) {
        int jl = w * 64 + jj * 2 + half;
        float4 hv = *(const float4*)&hb[jl * DD + d4];   // contiguous 1 KB/wave
        float4 pp = p4[jl];                               // b128 broadcast
        A0.x = fmaf(pp.x, hv.x, A0.x); A0.y = fmaf(pp.x, hv.y, A0.y);
        A0.z = fmaf(pp.x, hv.z, A0.z); A0.w = fmaf(pp.x, hv.w, A0.w);
        A1.x = fmaf(pp.y, hv.x, A1.x); A1.y = fmaf(pp.y, hv.y, A1.y);
        A1.z = fmaf(pp.y, hv.z, A1.z); A1.w = fmaf(pp.y, hv.w, A1.w);
        A2.x = fmaf(pp.z, hv.x, A2.x); A2.y = fmaf(pp.z, hv.y, A2.y);
        A2.z = fmaf(pp.z, hv.z, A2.z); A2.w = fmaf(pp.z, hv.w, A2.w);
        A3.x = fmaf(pp.w, hv.x, A3.x); A3.y = fmaf(pp.w, hv.y, A3.y);
        A3.z = fmaf(pp.w, hv.z, A3.z); A3.w = fmaf(pp.w, hv.w, A3.w);
    }
    // fold the two halves (different keys, same (q,d))
#define FOLD(A) A.x += __shfl_xor(A.x, 32); A.y += __shfl_xor(A.y, 32); \
                A.z += __shfl_xor(A.z, 32); A.w += __shfl_xor(A.w, 32);
    FOLD(A0) FOLD(A1) FOLD(A2) FOLD(A3)
#undef FOLD
    if (half == 0) {
        *(float4*)&red[w][0][d4] = A0;
        *(float4*)&red[w][1][d4] = A1;
        *(float4*)&red[w][2][d4] = A2;
        *(float4*)&red[w][3][d4] = A3;
    }
    __syncthreads();

    // ---- epilogue: sum 8 wave-partials, normalize, store ----
    {
        int q = t >> 7, d = t & 127;
        float o = 0.f;
#pragma unroll
        for (int k = 0; k < 8; ++k) o += red[k][q][d];
        const float* wf = (const float*)wsum4;
        float qs = 0.f;
#pragma unroll
        for (int k = 0; k < 8; ++k) qs += wf[k * 4 + q];
        out[(size_t)(row0 + q) * DD + d] = o * __builtin_amdgcn_rcpf(qs);
    }
}

extern "C" void kernel_launch(void* const* d_in, const int* in_sizes, int n_in,
                              void* d_out, int out_size, void* d_ws, size_t ws_size,
                              hipStream_t stream) {
    const float* s = (const float*)d_in[0];
    const float* h = (const float*)d_in[1];
    const float* W = (const float*)d_in[2];
    const float* U = (const float*)d_in[3];
    const float* v = (const float*)d_in[4];
    float* out = (float*)d_out;
    float* ws  = (float*)d_ws;

    float* Es   = ws;                     // 1024*128 floats: exp(2*s@W)
    float* EhT4 = ws + 131072;            // 1024*128 floats: exp(2*h@U), tiled

    hipLaunchKernelGGL(proj_kernel, dim3(512), dim3(256), 0, stream,
                       s, h, W, U, Es, EhT4);
    hipLaunchKernelGGL(attn_kernel, dim3(NK / 4), dim3(512), 0, stream,
                       Es, EhT4, h, v, out);
}